// Round 11
// baseline (161.040 us; speedup 1.0000x reference)
//
#include <hip/hip_runtime.h>

#define NN    100000
#define NE    640000
#define DIM   128
#define NPT   32    // nodes per fused tile
#define PAD   4     // LDS row pad: stride 528 B, 16B-aligned
#define WCH   16    // W chunk width -> Ws 8.4 KB; total LDS 25.3 KB, 6 blk/CU
#define TILE  1024  // scan tile (elements per block)
#define NBLK  98    // ceil(NN / TILE)

typedef unsigned short ushortT;
typedef ushortT ushort8 __attribute__((ext_vector_type(8)));

__device__ __forceinline__ ushortT f2b(float f) {      // fp32 -> bf16 RNE
    unsigned b = __float_as_uint(f);
    return (ushortT)((b + 0x7FFFu + ((b >> 16) & 1u)) >> 16);
}
__device__ __forceinline__ float b2f(ushortT u) {      // bf16 -> fp32 exact
    return __uint_as_float(((unsigned)u) << 16);
}

// ws layout (4-byte units):
//   cnts [0, NN)  offs [NN, 2NN+4)  curs [2NN+4, 3NN+4)
//   esrc [3NN+4, +NE)  blksum [+128]  x_bf16 [(3NN+4+NE+128)*4 B, +NN*DIM*2 B]
//   total ~29.4 MB (fp32 fallback path used if ws_size smaller)

// ---------------------------------------------------------------------------
// 0) Cast x -> bf16 copy (8 floats/thread) and zero cnts (replaces memset).
// ---------------------------------------------------------------------------
__global__ __launch_bounds__(256) void xcast_k(
    const float* __restrict__ x, ushortT* __restrict__ xb,
    unsigned* __restrict__ cnts)
{
    int gid = blockIdx.x * 256 + threadIdx.x;
    if (gid < NN / 4)
        reinterpret_cast<uint4*>(cnts)[gid] = make_uint4(0u, 0u, 0u, 0u);
    int i = gid * 8;
    if (i < NN * DIM) {
        float4 f0 = *reinterpret_cast<const float4*>(x + i);
        float4 f1 = *reinterpret_cast<const float4*>(x + i + 4);
        ushort8 u;
        u[0] = f2b(f0.x); u[1] = f2b(f0.y); u[2] = f2b(f0.z); u[3] = f2b(f0.w);
        u[4] = f2b(f1.x); u[5] = f2b(f1.y); u[6] = f2b(f1.z); u[7] = f2b(f1.w);
        *reinterpret_cast<ushort8*>(xb + i) = u;
    }
}

// ---------------------------------------------------------------------------
// 1) Histogram of targets.
// ---------------------------------------------------------------------------
__global__ __launch_bounds__(256) void hist_k(
    const int* __restrict__ ei, unsigned* __restrict__ cnts)
{
    int e = blockIdx.x * 256 + threadIdx.x;
    if (e >= NE) return;
    int t = ei[NE + e];
    if ((unsigned)t >= NN) return;
    atomicAdd(&cnts[t], 1u);
}

// ---------------------------------------------------------------------------
// 2a) Per-block sums of 1024-elem tiles.
// ---------------------------------------------------------------------------
__global__ __launch_bounds__(256) void scan_a_k(
    const unsigned* __restrict__ cnts, unsigned* __restrict__ blksum)
{
    __shared__ unsigned red[4];
    int t    = threadIdx.x;
    int base = blockIdx.x * TILE + t * 4;
    unsigned v = 0;
    if (base + 3 < NN) {
        uint4 u = *reinterpret_cast<const uint4*>(cnts + base);
        v = u.x + u.y + u.z + u.w;
    } else {
        for (int k = 0; k < 4; ++k) if (base + k < NN) v += cnts[base + k];
    }
    #pragma unroll
    for (int off = 32; off; off >>= 1) v += __shfl_down(v, off);
    if ((t & 63) == 0) red[t >> 6] = v;
    __syncthreads();
    if (t == 0) blksum[blockIdx.x] = red[0] + red[1] + red[2] + red[3];
}

// ---------------------------------------------------------------------------
// 2b) Per-block scan (+ inline base from blksum) -> offs, curs.
// ---------------------------------------------------------------------------
__global__ __launch_bounds__(256) void scan_c_k(
    const unsigned* __restrict__ cnts,
    const unsigned* __restrict__ blksum,
    unsigned* __restrict__ offs,
    unsigned* __restrict__ curs)
{
    __shared__ unsigned ps[256];
    __shared__ unsigned lsum[4];
    int t    = threadIdx.x;
    int bid  = blockIdx.x;
    int base = bid * TILE + t * 4;

    unsigned part = 0;
    for (int j = t; j < bid; j += 256) part += blksum[j];
    #pragma unroll
    for (int off = 32; off; off >>= 1) part += __shfl_down(part, off);
    if ((t & 63) == 0) lsum[t >> 6] = part;

    unsigned v0 = 0, v1 = 0, v2 = 0, v3 = 0;
    if (base + 3 < NN) {
        uint4 u = *reinterpret_cast<const uint4*>(cnts + base);
        v0 = u.x; v1 = u.y; v2 = u.z; v3 = u.w;
    } else {
        if (base     < NN) v0 = cnts[base];
        if (base + 1 < NN) v1 = cnts[base + 1];
        if (base + 2 < NN) v2 = cnts[base + 2];
    }
    ps[t] = v0 + v1 + v2 + v3;
    __syncthreads();
    for (int off = 1; off < 256; off <<= 1) {
        unsigned u = (t >= off) ? ps[t - off] : 0u;
        __syncthreads();
        ps[t] += u;
        __syncthreads();
    }
    unsigned blkbase = lsum[0] + lsum[1] + lsum[2] + lsum[3];
    unsigned run = blkbase + ((t == 0) ? 0u : ps[t - 1]);
    unsigned o0 = run, o1 = o0 + v0, o2 = o1 + v1, o3 = o2 + v2;
    if (base + 3 < NN) {
        *reinterpret_cast<uint4*>(offs + base) = make_uint4(o0, o1, o2, o3);
        *reinterpret_cast<uint4*>(curs + base) = make_uint4(o0, o1, o2, o3);
    } else {
        if (base     < NN) { offs[base]     = o0; curs[base]     = o0; }
        if (base + 1 < NN) { offs[base + 1] = o1; curs[base + 1] = o1; }
        if (base + 2 < NN) { offs[base + 2] = o2; curs[base + 2] = o2; }
    }
    if (bid == NBLK - 1 && t == 255) offs[NN] = blkbase + ps[255];
}

// ---------------------------------------------------------------------------
// 3) Bin edges by target.
// ---------------------------------------------------------------------------
__global__ __launch_bounds__(256) void bin_k(
    const int* __restrict__ ei,
    unsigned* __restrict__ curs,
    int* __restrict__ esrc)
{
    int e = blockIdx.x * 256 + threadIdx.x;
    if (e >= NE) return;
    int s = ei[e];
    int t = ei[NE + e];
    if ((unsigned)s >= NN || (unsigned)t >= NN) return;
    unsigned pos = atomicAdd(&curs[t], 1u);
    esrc[pos] = s;
}

// ---------------------------------------------------------------------------
// 4) Fused mean(bf16 gather) + fp32 linear + residual.
//    Gather traffic halved: 32B/thread/edge from x_bf16 (25.6 MB footprint).
// ---------------------------------------------------------------------------
__global__ __launch_bounds__(256) void fused_bf16_k(
    const float* __restrict__ x,
    const ushortT* __restrict__ xb,
    const float* __restrict__ W,
    const float* __restrict__ b,
    const unsigned* __restrict__ offs,
    const int* __restrict__ esrc,
    float* __restrict__ out)
{
    __shared__ float Ws[WCH][DIM + PAD];
    __shared__ float mean_s[NPT][DIM + PAD];

    const int t    = threadIdx.x;
    const int base = blockIdx.x * NPT;

    {
        int sn   = t >> 3;
        int so   = (t & 7) * 16;
        int node = base + sn;
        unsigned beg = offs[node], end = offs[node + 1];
        float aa[16], cc[16];
        #pragma unroll
        for (int k = 0; k < 16; ++k) { aa[k] = 0.f; cc[k] = 0.f; }

        unsigned j = beg;
        int s0 = 0, s1 = 0;
        if (j + 1 < end) { s0 = esrc[j]; s1 = esrc[j + 1]; }
        while (j + 1 < end) {
            unsigned jn = j + 2;
            int t0 = 0, t1 = 0;
            if (jn + 1 < end) { t0 = esrc[jn]; t1 = esrc[jn + 1]; }
            const ushort8* r0 = reinterpret_cast<const ushort8*>(xb + (size_t)s0 * DIM + so);
            const ushort8* r1 = reinterpret_cast<const ushort8*>(xb + (size_t)s1 * DIM + so);
            ushort8 p0 = r0[0], p1 = r0[1];
            ushort8 q0 = r1[0], q1 = r1[1];
            #pragma unroll
            for (int k = 0; k < 8; ++k) {
                aa[k]     += b2f(p0[k]);
                aa[k + 8] += b2f(p1[k]);
                cc[k]     += b2f(q0[k]);
                cc[k + 8] += b2f(q1[k]);
            }
            s0 = t0; s1 = t1;
            j = jn;
        }
        if (j < end) {   // odd tail edge
            int s = esrc[j];
            const ushort8* r0 = reinterpret_cast<const ushort8*>(xb + (size_t)s * DIM + so);
            ushort8 p0 = r0[0], p1 = r0[1];
            #pragma unroll
            for (int k = 0; k < 8; ++k) {
                aa[k]     += b2f(p0[k]);
                aa[k + 8] += b2f(p1[k]);
            }
        }
        float inv = 1.0f / fmaxf((float)(end - beg), 1.0f);
        #pragma unroll
        for (int k = 0; k < 16; ++k) aa[k] = (aa[k] + cc[k]) * inv;
        #pragma unroll
        for (int k = 0; k < 16; ++k) mean_s[sn][so + k] = aa[k];
    }

    const int og = (t & 31) * 4;
    const int ng = (t >> 5) * 4;

    float4 acc[4];
    #pragma unroll
    for (int n = 0; n < 4; ++n) acc[n] = make_float4(0.f, 0.f, 0.f, 0.f);

    for (int c = 0; c < DIM / WCH; ++c) {
        __syncthreads();
        #pragma unroll
        for (int k = 0; k < (DIM * WCH) / 256; ++k) {
            int idx = t + k * 256;
            int o   = idx >> 4;
            int il  = idx & 15;
            Ws[il][o] = W[o * DIM + c * WCH + il];
        }
        __syncthreads();

        #pragma unroll
        for (int i = 0; i < WCH; i += 4) {
            float4 m4[4];
            #pragma unroll
            for (int n = 0; n < 4; ++n)
                m4[n] = *reinterpret_cast<const float4*>(&mean_s[ng + n][c * WCH + i]);
            #pragma unroll
            for (int j = 0; j < 4; ++j) {
                float4 w = *reinterpret_cast<const float4*>(&Ws[i + j][og]);
                #pragma unroll
                for (int n = 0; n < 4; ++n) {
                    float m = (j == 0) ? m4[n].x : (j == 1) ? m4[n].y
                            : (j == 2) ? m4[n].z : m4[n].w;
                    acc[n].x += m * w.x;
                    acc[n].y += m * w.y;
                    acc[n].z += m * w.z;
                    acc[n].w += m * w.w;
                }
            }
        }
    }

    float4 bv = *reinterpret_cast<const float4*>(b + og);
    #pragma unroll
    for (int n = 0; n < 4; ++n) {
        int node = base + ng + n;
        float4 xv = *reinterpret_cast<const float4*>(x + (size_t)node * DIM + og);
        float4 o4;
        o4.x = xv.x + bv.x + acc[n].x;
        o4.y = xv.y + bv.y + acc[n].y;
        o4.z = xv.z + bv.z + acc[n].z;
        o4.w = xv.w + bv.w + acc[n].w;
        *reinterpret_cast<float4*>(out + (size_t)node * DIM + og) = o4;
    }
}

// ---------------------------------------------------------------------------
// 4') fp32 fallback (r10 fused_k) — used only if ws_size can't hold x_bf16.
// ---------------------------------------------------------------------------
__global__ __launch_bounds__(256) void fused_fp32_k(
    const float* __restrict__ x,
    const float* __restrict__ W,
    const float* __restrict__ b,
    const unsigned* __restrict__ offs,
    const int* __restrict__ esrc,
    float* __restrict__ out)
{
    __shared__ float Ws[WCH][DIM + PAD];
    __shared__ float mean_s[NPT][DIM + PAD];

    const int t    = threadIdx.x;
    const int base = blockIdx.x * NPT;

    {
        int sn   = t >> 3;
        int so   = (t & 7) * 16;
        int node = base + sn;
        unsigned beg = offs[node], end = offs[node + 1];
        float4 a0 = make_float4(0.f, 0.f, 0.f, 0.f), a1 = a0, a2 = a0, a3 = a0;
        int s = (beg < end) ? esrc[beg] : 0;
        for (unsigned j = beg; j < end; ++j) {
            int snext = (j + 1 < end) ? esrc[j + 1] : 0;
            const float4* xr = reinterpret_cast<const float4*>(x + (size_t)s * DIM + so);
            float4 g0 = xr[0], g1 = xr[1], g2 = xr[2], g3 = xr[3];
            a0.x += g0.x; a0.y += g0.y; a0.z += g0.z; a0.w += g0.w;
            a1.x += g1.x; a1.y += g1.y; a1.z += g1.z; a1.w += g1.w;
            a2.x += g2.x; a2.y += g2.y; a2.z += g2.z; a2.w += g2.w;
            a3.x += g3.x; a3.y += g3.y; a3.z += g3.z; a3.w += g3.w;
            s = snext;
        }
        float inv = 1.0f / fmaxf((float)(end - beg), 1.0f);
        a0.x *= inv; a0.y *= inv; a0.z *= inv; a0.w *= inv;
        a1.x *= inv; a1.y *= inv; a1.z *= inv; a1.w *= inv;
        a2.x *= inv; a2.y *= inv; a2.z *= inv; a2.w *= inv;
        a3.x *= inv; a3.y *= inv; a3.z *= inv; a3.w *= inv;
        *reinterpret_cast<float4*>(&mean_s[sn][so +  0]) = a0;
        *reinterpret_cast<float4*>(&mean_s[sn][so +  4]) = a1;
        *reinterpret_cast<float4*>(&mean_s[sn][so +  8]) = a2;
        *reinterpret_cast<float4*>(&mean_s[sn][so + 12]) = a3;
    }

    const int og = (t & 31) * 4;
    const int ng = (t >> 5) * 4;

    float4 acc[4];
    #pragma unroll
    for (int n = 0; n < 4; ++n) acc[n] = make_float4(0.f, 0.f, 0.f, 0.f);

    for (int c = 0; c < DIM / WCH; ++c) {
        __syncthreads();
        #pragma unroll
        for (int k = 0; k < (DIM * WCH) / 256; ++k) {
            int idx = t + k * 256;
            int o   = idx >> 4;
            int il  = idx & 15;
            Ws[il][o] = W[o * DIM + c * WCH + il];
        }
        __syncthreads();

        #pragma unroll
        for (int i = 0; i < WCH; i += 4) {
            float4 m4[4];
            #pragma unroll
            for (int n = 0; n < 4; ++n)
                m4[n] = *reinterpret_cast<const float4*>(&mean_s[ng + n][c * WCH + i]);
            #pragma unroll
            for (int j = 0; j < 4; ++j) {
                float4 w = *reinterpret_cast<const float4*>(&Ws[i + j][og]);
                #pragma unroll
                for (int n = 0; n < 4; ++n) {
                    float m = (j == 0) ? m4[n].x : (j == 1) ? m4[n].y
                            : (j == 2) ? m4[n].z : m4[n].w;
                    acc[n].x += m * w.x;
                    acc[n].y += m * w.y;
                    acc[n].z += m * w.z;
                    acc[n].w += m * w.w;
                }
            }
        }
    }

    float4 bv = *reinterpret_cast<const float4*>(b + og);
    #pragma unroll
    for (int n = 0; n < 4; ++n) {
        int node = base + ng + n;
        float4 xv = *reinterpret_cast<const float4*>(x + (size_t)node * DIM + og);
        float4 o4;
        o4.x = xv.x + bv.x + acc[n].x;
        o4.y = xv.y + bv.y + acc[n].y;
        o4.z = xv.z + bv.z + acc[n].z;
        o4.w = xv.w + bv.w + acc[n].w;
        *reinterpret_cast<float4*>(out + (size_t)node * DIM + og) = o4;
    }
}

extern "C" void kernel_launch(void* const* d_in, const int* in_sizes, int n_in,
                              void* d_out, int out_size, void* d_ws, size_t ws_size,
                              hipStream_t stream) {
    const float* x  = (const float*)d_in[0];
    const int*   ei = (const int*)d_in[1];     // int32 per harness contract
    const float* W  = (const float*)d_in[2];
    const float* b  = (const float*)d_in[3];
    float* out = (float*)d_out;

    unsigned* cnts   = (unsigned*)d_ws;
    unsigned* offs   = cnts + NN;
    unsigned* curs   = cnts + 2 * NN + 4;
    int*      esrc   = (int*)(cnts + 3 * NN + 4);
    unsigned* blksum = (unsigned*)(esrc + NE);          // 128
    ushortT*  xb     = (ushortT*)(blksum + 128);        // NN*DIM bf16

    size_t need = ((size_t)(3 * NN + 4 + NE + 128)) * 4 + (size_t)NN * DIM * 2;
    bool use_bf16 = (ws_size >= need);

    if (use_bf16) {
        xcast_k<<<(NN * DIM / 8 + 255) / 256, 256, 0, stream>>>(x, xb, cnts);
    } else {
        hipMemsetAsync(cnts, 0, (size_t)NN * sizeof(unsigned), stream);
    }

    hist_k  <<<(NE + 255) / 256, 256, 0, stream>>>(ei, cnts);
    scan_a_k<<<NBLK, 256, 0, stream>>>(cnts, blksum);
    scan_c_k<<<NBLK, 256, 0, stream>>>(cnts, blksum, offs, curs);
    bin_k   <<<(NE + 255) / 256, 256, 0, stream>>>(ei, curs, esrc);

    if (use_bf16)
        fused_bf16_k<<<NN / NPT, 256, 0, stream>>>(x, xb, W, b, offs, esrc, out);
    else
        fused_fp32_k<<<NN / NPT, 256, 0, stream>>>(x, W, b, offs, esrc, out);
}